// Round 7
// baseline (66.597 us; speedup 1.0000x reference)
//
#include <hip/hip_runtime.h>
#include <math.h>

#define BB 64
#define SS 32
#define DD 1024
#define HH 1024
#define NG 40          // group slots (worst case Sum ceil(c_s/8) = 36)
#define GG 8           // samples per group

__device__ __forceinline__ float gelu_exact(float x) {
    return 0.5f * x * (1.0f + erff(x * 0.7071067811865476f));
}

// ws layout:
//   [0, 256)        idx int[64]
//   [256, 8448)     logits float[64][32]
//   [8448, 8608)    grp_scene int[NG]
//   [8704, 9984)    grp_samp  int[NG][GG]
//   [32768, ...)    part float[2][64][DSPL][1024]
#define WS_LOGITS 256
#define WS_GSCENE 8448
#define WS_GSAMP  8704
#define WS_PART   32768

// ---------------- Kernel A1: one logit per block ----------------
__global__ __launch_bounds__(256) void logits_kernel(
    const float* __restrict__ descs_t, const float* __restrict__ descs_rot,
    const float* __restrict__ scene_w, float* __restrict__ logits)
{
    const int s = blockIdx.x, b = blockIdx.y;
    const int tid = threadIdx.x, lane = tid & 63, wave = tid >> 6;

    const float4* t4 = (const float4*)(descs_t  + ((size_t)b * SS + s) * DD);
    const float4* r4 = (const float4*)(descs_rot + ((size_t)b * SS + s) * DD);
    const float4* w4t = (const float4*)(scene_w);
    const float4* w4r = (const float4*)(scene_w + DD);

    float4 a = t4[tid], w = w4t[tid];
    float acc = a.x*w.x + a.y*w.y + a.z*w.z + a.w*w.w;
    float4 a2 = r4[tid], w2 = w4r[tid];
    acc += a2.x*w2.x + a2.y*w2.y + a2.z*w2.z + a2.w*w2.w;

    #pragma unroll
    for (int off = 32; off >= 1; off >>= 1) acc += __shfl_xor(acc, off, 64);

    __shared__ float red[4];
    if (lane == 0) red[wave] = acc;
    __syncthreads();
    if (tid == 0) logits[b * SS + s] = red[0] + red[1] + red[2] + red[3];
}

// ---------------- Kernel A2: softmax/argmax + group build (1 wave) ----------------
__global__ __launch_bounds__(64) void finalize_scene_kernel(
    const float* __restrict__ scene_b, float* __restrict__ logits,
    int* __restrict__ idx_ws, int* __restrict__ grp_scene, int* __restrict__ grp_samp,
    float* __restrict__ out)
{
    const int b = threadIdx.x;
    const float bias = scene_b[0];
    float lg[SS];
    float m = -1e30f; int am = 0;
    #pragma unroll
    for (int s = 0; s < SS; ++s) {
        lg[s] = logits[b * SS + s] + bias;
        if (lg[s] > m) { m = lg[s]; am = s; }   // first-max tie-break
    }
    float sum = 0.f;
    #pragma unroll
    for (int s = 0; s < SS; ++s) sum += expf(lg[s] - m);
    const float lse = m + logf(sum);
    #pragma unroll
    for (int s = 0; s < SS; ++s) out[BB * 7 + b * SS + s] = lg[s] - lse;
    idx_ws[b] = am;

    // ---- build groups of <=GG samples per scene ----
    __shared__ int sh_cnt[SS];
    __shared__ int sh_base[SS];
    __shared__ int sh_scene[NG];
    __shared__ int sh_samp[NG][GG];

    for (int i = b; i < NG; i += 64) sh_scene[i] = -1;
    for (int i = b; i < NG * GG; i += 64) ((int*)sh_samp)[i] = -1;

    int rank = 0;
    for (int s = 0; s < SS; ++s) {
        unsigned long long mk = __ballot(am == s);
        if (am == s) rank = __popcll(mk & ((1ull << b) - 1ull));
        if (b == s) sh_cnt[s] = (int)__popcll(mk);
    }
    __syncthreads();
    if (b == 0) {
        int acc = 0;
        for (int s = 0; s < SS; ++s) {
            sh_base[s] = acc;
            acc += (sh_cnt[s] + GG - 1) / GG;
        }
    }
    __syncthreads();
    {
        const int g = sh_base[am] + rank / GG;
        const int slot = rank % GG;
        sh_samp[g][slot] = b;
        if (slot == 0) sh_scene[g] = am;
    }
    __syncthreads();
    for (int i = b; i < NG; i += 64) grp_scene[i] = sh_scene[i];
    for (int i = b; i < NG * GG; i += 64) grp_samp[i] = ((int*)sh_samp)[i];
}

// ---------------- Kernel B: layer-1 matvec, uniform one-pass groups ----------------
// grid (DSPL, NG, 2). Per thread: 4 consecutive H-cols, GG accumulators.
// Plain 4-row batches, compiler-scheduled (no sched_barrier pinning), lean VGPR.
template<int DSPL>
__global__ __launch_bounds__(256) void layer1_kernel(
    const float* __restrict__ descs_t, const float* __restrict__ descs_rot,
    const float* __restrict__ Wt1, const float* __restrict__ Wr1,
    const int* __restrict__ grp_scene, const int* __restrict__ grp_samp,
    float* __restrict__ part)
{
    constexpr int DS = DD / DSPL;      // rows per block
    const int dsp  = blockIdx.x;
    const int g    = blockIdx.y;
    const int head = blockIdx.z;
    const int tid  = threadIdx.x;

    const int s = grp_scene[g];
    if (s < 0) return;

    __shared__ int   sh_b[GG];
    __shared__ float sh_g[DS][GG];     // transposed: row d holds all GG samples
    if (tid < GG) sh_b[tid] = grp_samp[g * GG + tid];
    __syncthreads();

    const float* descs = head ? descs_rot : descs_t;
    for (int t = tid; t < GG * (DS / 4); t += 256) {
        const int p = t / (DS / 4);
        const int c = t % (DS / 4);
        const int b = sh_b[p];
        float4 v = make_float4(0.f, 0.f, 0.f, 0.f);
        if (b >= 0)
            v = ((const float4*)(descs + ((size_t)b * SS + s) * DD + dsp * DS))[c];
        sh_g[c * 4 + 0][p] = v.x;
        sh_g[c * 4 + 1][p] = v.y;
        sh_g[c * 4 + 2][p] = v.z;
        sh_g[c * 4 + 3][p] = v.w;
    }
    __syncthreads();

    const float* W = (head ? Wr1 : Wt1)
                   + (size_t)s * DD * HH + (size_t)dsp * DS * HH + tid * 4;

    float4 acc[GG];
    #pragma unroll
    for (int p = 0; p < GG; ++p) acc[p] = make_float4(0.f, 0.f, 0.f, 0.f);

    #pragma unroll 2
    for (int d0 = 0; d0 < DS; d0 += 4) {
        float4 w0 = *(const float4*)(W + (size_t)(d0 + 0) * HH);
        float4 w1 = *(const float4*)(W + (size_t)(d0 + 1) * HH);
        float4 w2 = *(const float4*)(W + (size_t)(d0 + 2) * HH);
        float4 w3 = *(const float4*)(W + (size_t)(d0 + 3) * HH);
        #pragma unroll
        for (int r = 0; r < 4; ++r) {
            const float4 wv = (r == 0) ? w0 : (r == 1) ? w1 : (r == 2) ? w2 : w3;
            const float4 ga = *(const float4*)&sh_g[d0 + r][0];  // broadcast
            const float4 gb = *(const float4*)&sh_g[d0 + r][4];
            acc[0].x += ga.x*wv.x; acc[0].y += ga.x*wv.y; acc[0].z += ga.x*wv.z; acc[0].w += ga.x*wv.w;
            acc[1].x += ga.y*wv.x; acc[1].y += ga.y*wv.y; acc[1].z += ga.y*wv.z; acc[1].w += ga.y*wv.w;
            acc[2].x += ga.z*wv.x; acc[2].y += ga.z*wv.y; acc[2].z += ga.z*wv.z; acc[2].w += ga.z*wv.w;
            acc[3].x += ga.w*wv.x; acc[3].y += ga.w*wv.y; acc[3].z += ga.w*wv.z; acc[3].w += ga.w*wv.w;
            acc[4].x += gb.x*wv.x; acc[4].y += gb.x*wv.y; acc[4].z += gb.x*wv.z; acc[4].w += gb.x*wv.w;
            acc[5].x += gb.y*wv.x; acc[5].y += gb.y*wv.y; acc[5].z += gb.y*wv.z; acc[5].w += gb.y*wv.w;
            acc[6].x += gb.z*wv.x; acc[6].y += gb.z*wv.y; acc[6].z += gb.z*wv.z; acc[6].w += gb.z*wv.w;
            acc[7].x += gb.w*wv.x; acc[7].y += gb.w*wv.y; acc[7].z += gb.w*wv.z; acc[7].w += gb.w*wv.w;
        }
    }

    #pragma unroll
    for (int p = 0; p < GG; ++p) {
        const int b = sh_b[p];
        if (b >= 0) {
            float* dst = part + (((size_t)(head * BB + b) * DSPL + dsp) * HH) + tid * 4;
            *(float4*)dst = acc[p];
        }
    }
}

// ---------------- Kernel C: bias + GELU + layer-2 + pose output ----------------
template<int DSPL>
__global__ __launch_bounds__(256) void head_out_kernel(
    const float* __restrict__ bt1, const float* __restrict__ Wt2, const float* __restrict__ bt2,
    const float* __restrict__ br1, const float* __restrict__ Wr2, const float* __restrict__ br2,
    const int* __restrict__ idx_ws, const float* __restrict__ part,
    float* __restrict__ out)
{
    const int b   = blockIdx.x;
    const int tid = threadIdx.x;
    const int s   = idx_ws[b];

    __shared__ float sh_h[2][HH];
    __shared__ float sh_red[7][4];

    #pragma unroll
    for (int head = 0; head < 2; ++head) {
        const float* b1 = (head ? br1 : bt1) + (size_t)s * HH;
        const float* p0 = part + ((size_t)(head * BB + b) * DSPL) * HH;
        const int j = tid * 4;
        float4 a = *(const float4*)(p0 + j);
        #pragma unroll 8
        for (int dsp = 1; dsp < DSPL; ++dsp) {
            float4 q = *(const float4*)(p0 + (size_t)dsp * HH + j);
            a.x += q.x; a.y += q.y; a.z += q.z; a.w += q.w;
        }
        float4 bb = *(const float4*)(b1 + j);
        sh_h[head][j + 0] = gelu_exact(a.x + bb.x);
        sh_h[head][j + 1] = gelu_exact(a.y + bb.y);
        sh_h[head][j + 2] = gelu_exact(a.z + bb.z);
        sh_h[head][j + 3] = gelu_exact(a.w + bb.w);
    }
    __syncthreads();

    const float* wt2 = Wt2 + (size_t)s * HH * 3;
    const float* wr2 = Wr2 + (size_t)s * HH * 4;
    float pa[7] = {0.f, 0.f, 0.f, 0.f, 0.f, 0.f, 0.f};
    for (int j = tid; j < HH; j += 256) {
        float ht = sh_h[0][j];
        float hr = sh_h[1][j];
        pa[0] += ht * wt2[j * 3 + 0];
        pa[1] += ht * wt2[j * 3 + 1];
        pa[2] += ht * wt2[j * 3 + 2];
        pa[3] += hr * wr2[j * 4 + 0];
        pa[4] += hr * wr2[j * 4 + 1];
        pa[5] += hr * wr2[j * 4 + 2];
        pa[6] += hr * wr2[j * 4 + 3];
    }
    const int lane = tid & 63, wave = tid >> 6;
    #pragma unroll
    for (int o = 0; o < 7; ++o) {
        float v = pa[o];
        #pragma unroll
        for (int off = 32; off >= 1; off >>= 1) v += __shfl_xor(v, off, 64);
        if (lane == 0) sh_red[o][wave] = v;
    }
    __syncthreads();
    if (tid < 7) {
        float v = sh_red[tid][0] + sh_red[tid][1] + sh_red[tid][2] + sh_red[tid][3];
        float bias = (tid < 3) ? bt2[(size_t)s * 3 + tid] : br2[(size_t)s * 4 + (tid - 3)];
        out[b * 7 + tid] = v + bias;
    }
}

template<int DSPL>
static void launch_pipeline(const float* descs_t, const float* descs_rot,
                            const float* Wt1, const float* Wr1,
                            const float* bt1, const float* Wt2, const float* bt2,
                            const float* br1, const float* Wr2, const float* br2,
                            int* idx_ws, int* grp_scene, int* grp_samp, float* part,
                            float* out, hipStream_t stream) {
    layer1_kernel<DSPL><<<dim3(DSPL, NG, 2), dim3(256), 0, stream>>>(
        descs_t, descs_rot, Wt1, Wr1, grp_scene, grp_samp, part);
    head_out_kernel<DSPL><<<dim3(BB), dim3(256), 0, stream>>>(
        bt1, Wt2, bt2, br1, Wr2, br2, idx_ws, part, out);
}

extern "C" void kernel_launch(void* const* d_in, const int* in_sizes, int n_in,
                              void* d_out, int out_size, void* d_ws, size_t ws_size,
                              hipStream_t stream) {
    const float* descs_t   = (const float*)d_in[0];
    const float* descs_rot = (const float*)d_in[1];
    const float* scene_w   = (const float*)d_in[2];
    const float* scene_b   = (const float*)d_in[3];
    const float* Wt1 = (const float*)d_in[4];
    const float* bt1 = (const float*)d_in[5];
    const float* Wt2 = (const float*)d_in[6];
    const float* bt2 = (const float*)d_in[7];
    const float* Wr1 = (const float*)d_in[8];
    const float* br1 = (const float*)d_in[9];
    const float* Wr2 = (const float*)d_in[10];
    const float* br2 = (const float*)d_in[11];
    float* out = (float*)d_out;

    int*   idx_ws    = (int*)d_ws;
    float* logits    = (float*)((char*)d_ws + WS_LOGITS);
    int*   grp_scene = (int*)((char*)d_ws + WS_GSCENE);
    int*   grp_samp  = (int*)((char*)d_ws + WS_GSAMP);
    float* part      = (float*)((char*)d_ws + WS_PART);

    logits_kernel<<<dim3(SS, BB), dim3(256), 0, stream>>>(
        descs_t, descs_rot, scene_w, logits);
    finalize_scene_kernel<<<dim3(1), dim3(64), 0, stream>>>(
        scene_b, logits, idx_ws, grp_scene, grp_samp, out);

    const size_t need32 = (size_t)WS_PART + (size_t)2 * BB * 32 * HH * sizeof(float);
    const size_t need16 = (size_t)WS_PART + (size_t)2 * BB * 16 * HH * sizeof(float);
    const size_t need8  = (size_t)WS_PART + (size_t)2 * BB * 8  * HH * sizeof(float);
    if (ws_size >= need32) {
        launch_pipeline<32>(descs_t, descs_rot, Wt1, Wr1, bt1, Wt2, bt2, br1, Wr2, br2,
                            idx_ws, grp_scene, grp_samp, part, out, stream);
    } else if (ws_size >= need16) {
        launch_pipeline<16>(descs_t, descs_rot, Wt1, Wr1, bt1, Wt2, bt2, br1, Wr2, br2,
                            idx_ws, grp_scene, grp_samp, part, out, stream);
    } else if (ws_size >= need8) {
        launch_pipeline<8>(descs_t, descs_rot, Wt1, Wr1, bt1, Wt2, bt2, br1, Wr2, br2,
                            idx_ws, grp_scene, grp_samp, part, out, stream);
    } else {
        launch_pipeline<4>(descs_t, descs_rot, Wt1, Wr1, bt1, Wt2, bt2, br1, Wr2, br2,
                            idx_ws, grp_scene, grp_samp, part, out, stream);
    }
}

// Round 8
// 60.774 us; speedup vs baseline: 1.0958x; 1.0958x over previous
//
#include <hip/hip_runtime.h>
#include <math.h>

#define BB 64
#define SS 32
#define DD 1024
#define HH 1024
#define NG 40          // group slots (worst case Sum ceil(c_s/8) = 36)
#define GG 8           // samples per group

__device__ __forceinline__ float gelu_exact(float x) {
    return 0.5f * x * (1.0f + erff(x * 0.7071067811865476f));
}

// async global->LDS, 16B per lane; LDS dest is wave-uniform base + lane*16
__device__ __forceinline__ void gload_lds16(const float* g, float* l) {
    typedef const __attribute__((address_space(1))) unsigned int GU;
    typedef __attribute__((address_space(3))) unsigned int LU;
    __builtin_amdgcn_global_load_lds((GU*)g, (LU*)l, 16, 0, 0);
}

// ws layout:
//   [0, 256)        idx int[64]
//   [256, 8448)     logits float[64][32]
//   [8448, 8608)    grp_scene int[NG]
//   [8704, 9984)    grp_samp  int[NG][GG]
//   [32768, ...)    part float[2][64][DSPL][1024]
#define WS_LOGITS 256
#define WS_GSCENE 8448
#define WS_GSAMP  8704
#define WS_PART   32768

// ---------------- Kernel A1: one logit per block ----------------
__global__ __launch_bounds__(256) void logits_kernel(
    const float* __restrict__ descs_t, const float* __restrict__ descs_rot,
    const float* __restrict__ scene_w, float* __restrict__ logits)
{
    const int s = blockIdx.x, b = blockIdx.y;
    const int tid = threadIdx.x, lane = tid & 63, wave = tid >> 6;

    const float4* t4 = (const float4*)(descs_t  + ((size_t)b * SS + s) * DD);
    const float4* r4 = (const float4*)(descs_rot + ((size_t)b * SS + s) * DD);
    const float4* w4t = (const float4*)(scene_w);
    const float4* w4r = (const float4*)(scene_w + DD);

    float4 a = t4[tid], w = w4t[tid];
    float acc = a.x*w.x + a.y*w.y + a.z*w.z + a.w*w.w;
    float4 a2 = r4[tid], w2 = w4r[tid];
    acc += a2.x*w2.x + a2.y*w2.y + a2.z*w2.z + a2.w*w2.w;

    #pragma unroll
    for (int off = 32; off >= 1; off >>= 1) acc += __shfl_xor(acc, off, 64);

    __shared__ float red[4];
    if (lane == 0) red[wave] = acc;
    __syncthreads();
    if (tid == 0) logits[b * SS + s] = red[0] + red[1] + red[2] + red[3];
}

// ---------------- Kernel A2: softmax/argmax + group build (1 wave) ----------------
__global__ __launch_bounds__(64) void finalize_scene_kernel(
    const float* __restrict__ scene_b, float* __restrict__ logits,
    int* __restrict__ idx_ws, int* __restrict__ grp_scene, int* __restrict__ grp_samp,
    float* __restrict__ out)
{
    const int b = threadIdx.x;
    const float bias = scene_b[0];
    float lg[SS];
    float m = -1e30f; int am = 0;
    #pragma unroll
    for (int s = 0; s < SS; ++s) {
        lg[s] = logits[b * SS + s] + bias;
        if (lg[s] > m) { m = lg[s]; am = s; }   // first-max tie-break
    }
    float sum = 0.f;
    #pragma unroll
    for (int s = 0; s < SS; ++s) sum += expf(lg[s] - m);
    const float lse = m + logf(sum);
    #pragma unroll
    for (int s = 0; s < SS; ++s) out[BB * 7 + b * SS + s] = lg[s] - lse;
    idx_ws[b] = am;

    // ---- build groups of <=GG samples per scene ----
    __shared__ int sh_cnt[SS];
    __shared__ int sh_base[SS];
    __shared__ int sh_scene[NG];
    __shared__ int sh_samp[NG][GG];

    for (int i = b; i < NG; i += 64) sh_scene[i] = -1;
    for (int i = b; i < NG * GG; i += 64) ((int*)sh_samp)[i] = -1;

    int rank = 0;
    for (int s = 0; s < SS; ++s) {
        unsigned long long mk = __ballot(am == s);
        if (am == s) rank = __popcll(mk & ((1ull << b) - 1ull));
        if (b == s) sh_cnt[s] = (int)__popcll(mk);
    }
    __syncthreads();
    if (b == 0) {
        int acc = 0;
        for (int s = 0; s < SS; ++s) {
            sh_base[s] = acc;
            acc += (sh_cnt[s] + GG - 1) / GG;
        }
    }
    __syncthreads();
    {
        const int g = sh_base[am] + rank / GG;
        const int slot = rank % GG;
        sh_samp[g][slot] = b;
        if (slot == 0) sh_scene[g] = am;
    }
    __syncthreads();
    for (int i = b; i < NG; i += 64) grp_scene[i] = sh_scene[i];
    for (int i = b; i < NG * GG; i += 64) grp_samp[i] = ((int*)sh_samp)[i];
}

// ---------------- Kernel B: layer-1 matvec, LDS-staged W (2-phase pipeline) ----------------
// grid (DSPL, NG, 2). W streamed via global_load_lds in 4-row (16 KB) chunks,
// double-buffered; accumulators stay lean (8 x float4), no VGPR load buffers.
template<int DSPL>
__global__ __launch_bounds__(256) void layer1_kernel(
    const float* __restrict__ descs_t, const float* __restrict__ descs_rot,
    const float* __restrict__ Wt1, const float* __restrict__ Wr1,
    const int* __restrict__ grp_scene, const int* __restrict__ grp_samp,
    float* __restrict__ part)
{
    constexpr int DS  = DD / DSPL;     // rows per block (64 at DSPL=16)
    constexpr int NCH = DS / 4;        // 4-row chunks
    const int dsp  = blockIdx.x;
    const int g    = blockIdx.y;
    const int head = blockIdx.z;
    const int tid  = threadIdx.x;
    const int wave = tid >> 6, lane = tid & 63;

    const int s = grp_scene[g];
    if (s < 0) return;

    __shared__ int   sh_b[GG];
    __shared__ float sh_g[DS][GG];         // transposed: row d holds all GG samples
    __shared__ float sh_w[2 * 4 * HH];     // 2 buffers x 4 rows x 1024 cols = 32 KB

    if (tid < GG) sh_b[tid] = grp_samp[g * GG + tid];
    __syncthreads();

    const float* descs = head ? descs_rot : descs_t;
    for (int t = tid; t < GG * (DS / 4); t += 256) {
        const int p = t / (DS / 4);
        const int c = t % (DS / 4);
        const int b = sh_b[p];
        float4 v = make_float4(0.f, 0.f, 0.f, 0.f);
        if (b >= 0)
            v = ((const float4*)(descs + ((size_t)b * SS + s) * DD + dsp * DS))[c];
        sh_g[c * 4 + 0][p] = v.x;
        sh_g[c * 4 + 1][p] = v.y;
        sh_g[c * 4 + 2][p] = v.z;
        sh_g[c * 4 + 3][p] = v.w;
    }

    // W base for this block's DS-row slice (no per-thread offset; DMA is per-lane)
    const float* W0 = (head ? Wr1 : Wt1)
                    + (size_t)s * DD * HH + (size_t)dsp * DS * HH;

    // stage chunk c (rows [c*4, c*4+4)) into buffer buf.
    // span k = wave*4+i covers row k/4, cols [(k%4)*256, +256); lane adds 4 floats.
    #define L1_STAGE(c, buf)                                                  \
        _Pragma("unroll")                                                     \
        for (int i = 0; i < 4; ++i) {                                         \
            const int k = wave * 4 + i;                                       \
            gload_lds16(W0 + (size_t)((c) * 4 + (k >> 2)) * HH                \
                           + (k & 3) * 256 + lane * 4,                        \
                        sh_w + (buf) * (4 * HH) + k * 256);                   \
        }

    float4 acc[GG];
    #pragma unroll
    for (int p = 0; p < GG; ++p) acc[p] = make_float4(0.f, 0.f, 0.f, 0.f);

    L1_STAGE(0, 0);
    __syncthreads();                       // drains vmcnt(0): buf0 resident, sh_g done

    int cur = 0;
    for (int c = 0; c < NCH; ++c) {
        if (c + 1 < NCH) { L1_STAGE(c + 1, cur ^ 1); }   // prefetch in flight under compute
        const float* wb = sh_w + cur * (4 * HH);
        const int d0 = c * 4;
        #pragma unroll
        for (int r = 0; r < 4; ++r) {
            const float4 wv = *(const float4*)(wb + r * HH + (tid << 2));
            const float4 ga = *(const float4*)&sh_g[d0 + r][0];   // broadcast
            const float4 gb = *(const float4*)&sh_g[d0 + r][4];
            acc[0].x += ga.x*wv.x; acc[0].y += ga.x*wv.y; acc[0].z += ga.x*wv.z; acc[0].w += ga.x*wv.w;
            acc[1].x += ga.y*wv.x; acc[1].y += ga.y*wv.y; acc[1].z += ga.y*wv.z; acc[1].w += ga.y*wv.w;
            acc[2].x += ga.z*wv.x; acc[2].y += ga.z*wv.y; acc[2].z += ga.z*wv.z; acc[2].w += ga.z*wv.w;
            acc[3].x += ga.w*wv.x; acc[3].y += ga.w*wv.y; acc[3].z += ga.w*wv.z; acc[3].w += ga.w*wv.w;
            acc[4].x += gb.x*wv.x; acc[4].y += gb.x*wv.y; acc[4].z += gb.x*wv.z; acc[4].w += gb.x*wv.w;
            acc[5].x += gb.y*wv.x; acc[5].y += gb.y*wv.y; acc[5].z += gb.y*wv.z; acc[5].w += gb.y*wv.w;
            acc[6].x += gb.z*wv.x; acc[6].y += gb.z*wv.y; acc[6].z += gb.z*wv.z; acc[6].w += gb.z*wv.w;
            acc[7].x += gb.w*wv.x; acc[7].y += gb.w*wv.y; acc[7].z += gb.w*wv.z; acc[7].w += gb.w*wv.w;
        }
        __syncthreads();                   // drain prefetch; protect cur buf reuse
        cur ^= 1;
    }
    #undef L1_STAGE

    #pragma unroll
    for (int p = 0; p < GG; ++p) {
        const int b = sh_b[p];
        if (b >= 0) {
            float* dst = part + (((size_t)(head * BB + b) * DSPL + dsp) * HH) + tid * 4;
            *(float4*)dst = acc[p];
        }
    }
}

// ---------------- Kernel C: bias + GELU + layer-2 + pose output ----------------
template<int DSPL>
__global__ __launch_bounds__(256) void head_out_kernel(
    const float* __restrict__ bt1, const float* __restrict__ Wt2, const float* __restrict__ bt2,
    const float* __restrict__ br1, const float* __restrict__ Wr2, const float* __restrict__ br2,
    const int* __restrict__ idx_ws, const float* __restrict__ part,
    float* __restrict__ out)
{
    const int b   = blockIdx.x;
    const int tid = threadIdx.x;
    const int s   = idx_ws[b];

    __shared__ float sh_h[2][HH];
    __shared__ float sh_red[7][4];

    #pragma unroll
    for (int head = 0; head < 2; ++head) {
        const float* b1 = (head ? br1 : bt1) + (size_t)s * HH;
        const float* p0 = part + ((size_t)(head * BB + b) * DSPL) * HH;
        const int j = tid * 4;
        float4 a = *(const float4*)(p0 + j);
        #pragma unroll 8
        for (int dsp = 1; dsp < DSPL; ++dsp) {
            float4 q = *(const float4*)(p0 + (size_t)dsp * HH + j);
            a.x += q.x; a.y += q.y; a.z += q.z; a.w += q.w;
        }
        float4 bb = *(const float4*)(b1 + j);
        sh_h[head][j + 0] = gelu_exact(a.x + bb.x);
        sh_h[head][j + 1] = gelu_exact(a.y + bb.y);
        sh_h[head][j + 2] = gelu_exact(a.z + bb.z);
        sh_h[head][j + 3] = gelu_exact(a.w + bb.w);
    }
    __syncthreads();

    const float* wt2 = Wt2 + (size_t)s * HH * 3;
    const float* wr2 = Wr2 + (size_t)s * HH * 4;
    float pa[7] = {0.f, 0.f, 0.f, 0.f, 0.f, 0.f, 0.f};
    for (int j = tid; j < HH; j += 256) {
        float ht = sh_h[0][j];
        float hr = sh_h[1][j];
        pa[0] += ht * wt2[j * 3 + 0];
        pa[1] += ht * wt2[j * 3 + 1];
        pa[2] += ht * wt2[j * 3 + 2];
        pa[3] += hr * wr2[j * 4 + 0];
        pa[4] += hr * wr2[j * 4 + 1];
        pa[5] += hr * wr2[j * 4 + 2];
        pa[6] += hr * wr2[j * 4 + 3];
    }
    const int lane = tid & 63, wave = tid >> 6;
    #pragma unroll
    for (int o = 0; o < 7; ++o) {
        float v = pa[o];
        #pragma unroll
        for (int off = 32; off >= 1; off >>= 1) v += __shfl_xor(v, off, 64);
        if (lane == 0) sh_red[o][wave] = v;
    }
    __syncthreads();
    if (tid < 7) {
        float v = sh_red[tid][0] + sh_red[tid][1] + sh_red[tid][2] + sh_red[tid][3];
        float bias = (tid < 3) ? bt2[(size_t)s * 3 + tid] : br2[(size_t)s * 4 + (tid - 3)];
        out[b * 7 + tid] = v + bias;
    }
}

template<int DSPL>
static void launch_pipeline(const float* descs_t, const float* descs_rot,
                            const float* Wt1, const float* Wr1,
                            const float* bt1, const float* Wt2, const float* bt2,
                            const float* br1, const float* Wr2, const float* br2,
                            int* idx_ws, int* grp_scene, int* grp_samp, float* part,
                            float* out, hipStream_t stream) {
    layer1_kernel<DSPL><<<dim3(DSPL, NG, 2), dim3(256), 0, stream>>>(
        descs_t, descs_rot, Wt1, Wr1, grp_scene, grp_samp, part);
    head_out_kernel<DSPL><<<dim3(BB), dim3(256), 0, stream>>>(
        bt1, Wt2, bt2, br1, Wr2, br2, idx_ws, part, out);
}

extern "C" void kernel_launch(void* const* d_in, const int* in_sizes, int n_in,
                              void* d_out, int out_size, void* d_ws, size_t ws_size,
                              hipStream_t stream) {
    const float* descs_t   = (const float*)d_in[0];
    const float* descs_rot = (const float*)d_in[1];
    const float* scene_w   = (const float*)d_in[2];
    const float* scene_b   = (const float*)d_in[3];
    const float* Wt1 = (const float*)d_in[4];
    const float* bt1 = (const float*)d_in[5];
    const float* Wt2 = (const float*)d_in[6];
    const float* bt2 = (const float*)d_in[7];
    const float* Wr1 = (const float*)d_in[8];
    const float* br1 = (const float*)d_in[9];
    const float* Wr2 = (const float*)d_in[10];
    const float* br2 = (const float*)d_in[11];
    float* out = (float*)d_out;

    int*   idx_ws    = (int*)d_ws;
    float* logits    = (float*)((char*)d_ws + WS_LOGITS);
    int*   grp_scene = (int*)((char*)d_ws + WS_GSCENE);
    int*   grp_samp  = (int*)((char*)d_ws + WS_GSAMP);
    float* part      = (float*)((char*)d_ws + WS_PART);

    logits_kernel<<<dim3(SS, BB), dim3(256), 0, stream>>>(
        descs_t, descs_rot, scene_w, logits);
    finalize_scene_kernel<<<dim3(1), dim3(64), 0, stream>>>(
        scene_b, logits, idx_ws, grp_scene, grp_samp, out);

    const size_t need16 = (size_t)WS_PART + (size_t)2 * BB * 16 * HH * sizeof(float);
    const size_t need8  = (size_t)WS_PART + (size_t)2 * BB * 8  * HH * sizeof(float);
    if (ws_size >= need16) {
        launch_pipeline<16>(descs_t, descs_rot, Wt1, Wr1, bt1, Wt2, bt2, br1, Wr2, br2,
                            idx_ws, grp_scene, grp_samp, part, out, stream);
    } else if (ws_size >= need8) {
        launch_pipeline<8>(descs_t, descs_rot, Wt1, Wr1, bt1, Wt2, bt2, br1, Wr2, br2,
                            idx_ws, grp_scene, grp_samp, part, out, stream);
    } else {
        launch_pipeline<4>(descs_t, descs_rot, Wt1, Wr1, bt1, Wt2, bt2, br1, Wr2, br2,
                            idx_ws, grp_scene, grp_samp, part, out, stream);
    }
}